// Round 1
// baseline (1600.606 us; speedup 1.0000x reference)
//
#include <hip/hip_runtime.h>
#include <hip/hip_bf16.h>
#include <stdint.h>

// ---------------------------------------------------------------------------
// TopoPool: z = x@W.T + b ; seg-softmax elev ; peaks (no higher in-neighbor) ;
// level-synchronous watershed BFS along descending edges (ties -> both) ;
// per-cluster per-feature max ; cluster softmax ; pooled = max_x * normed.
// All comparisons use z (monotone-equivalent to elev within a batch).
// ---------------------------------------------------------------------------

struct Ctl { int begin; int end; int count; int done; };

__device__ __forceinline__ unsigned encf(float f) {
  unsigned u = __float_as_uint(f);
  return (u & 0x80000000u) ? ~u : (u | 0x80000000u);
}
__device__ __forceinline__ float decf(unsigned u) {
  unsigned v = (u & 0x80000000u) ? (u & 0x7fffffffu) : ~u;
  return __uint_as_float(v);
}

// wave-per-node dot(x[v], W) + b; per-block LDS batch max -> global encoded max
__global__ void k_z(const float* __restrict__ x, const float* __restrict__ W,
                    const float* __restrict__ b, const int* __restrict__ batch,
                    float* __restrict__ z, unsigned* __restrict__ bmax_enc,
                    int N, int C) {
  __shared__ unsigned smax[1024];
  for (int i = threadIdx.x; i < 1024; i += blockDim.x) smax[i] = 0u;
  __syncthreads();
  int lane = threadIdx.x & 63;
  int wid = threadIdx.x >> 6;
  int wavesPerBlock = blockDim.x >> 6;
  int gw = blockIdx.x * wavesPerBlock + wid;
  int nw = gridDim.x * wavesPerBlock;
  float b0 = b[0];
  for (int v = gw; v < N; v += nw) {
    const float* xr = x + (size_t)v * C;
    float acc = 0.f;
    for (int f = lane * 4; f < C; f += 256) {
      float4 xv = *(const float4*)(xr + f);
      float4 wv = *(const float4*)(W + f);
      acc += xv.x * wv.x + xv.y * wv.y + xv.z * wv.z + xv.w * wv.w;
    }
    for (int off = 32; off > 0; off >>= 1) acc += __shfl_xor(acc, off, 64);
    if (lane == 0) {
      float zv = acc + b0;
      z[v] = zv;
      atomicMax(&smax[batch[v] & 1023], encf(zv));
    }
  }
  __syncthreads();
  for (int i = threadIdx.x; i < 1024; i += blockDim.x)
    if (smax[i]) atomicMax(&bmax_enc[i], smax[i]);
}

__global__ void k_e(const float* __restrict__ z, const int* __restrict__ batch,
                    const unsigned* __restrict__ bmax_enc, float* __restrict__ e,
                    float* __restrict__ bsum, int N) {
  __shared__ float ssum[1024];
  for (int i = threadIdx.x; i < 1024; i += blockDim.x) ssum[i] = 0.f;
  __syncthreads();
  int i = blockIdx.x * blockDim.x + threadIdx.x;
  if (i < N) {
    int bt = batch[i] & 1023;
    float ev = expf(z[i] - decf(bmax_enc[bt]));
    e[i] = ev;
    atomicAdd(&ssum[bt], ev);
  }
  __syncthreads();
  for (int t = threadIdx.x; t < 1024; t += blockDim.x)
    if (ssum[t] != 0.f) atomicAdd(&bsum[t], ssum[t]);
}

__global__ void k_elev(const float* __restrict__ e, const int* __restrict__ batch,
                       const float* __restrict__ bsum, float* __restrict__ elev_out, int N) {
  int i = blockIdx.x * blockDim.x + threadIdx.x;
  if (i < N) elev_out[i] = e[i] / bsum[batch[i] & 1023];
}

// per directed edge: notpeak[dst] if z[dst] < z[src]; count descending out-edges of src
__global__ void k_edges(const int* __restrict__ ei, const float* __restrict__ z,
                        int* __restrict__ notpeak, int* __restrict__ desc_cnt, int E) {
  int i = blockIdx.x * blockDim.x + threadIdx.x;
  if (i >= E) return;
  int s = ei[i], d = ei[E + i];
  float zs = z[s], zd = z[d];
  if (zd < zs) notpeak[d] = 1;
  if (zd <= zs) atomicAdd(&desc_cnt[s], 1);
}

// ---- generic chunked exclusive scan (chunk = 512, nchunks <= 1024) ----
__global__ void k_chunksum(const int* __restrict__ vals, int mode, int n,
                           int* __restrict__ chunksum) {
  __shared__ int s[512];
  int t = threadIdx.x;
  int i = blockIdx.x * 512 + t;
  int v = 0;
  if (i < n) { int a = vals[i]; v = mode ? (a == 0 ? 1 : 0) : a; }
  s[t] = v;
  __syncthreads();
  for (int off = 256; off > 0; off >>= 1) {
    if (t < off) s[t] += s[t + off];
    __syncthreads();
  }
  if (t == 0) chunksum[blockIdx.x] = s[0];
}

__global__ void k_chunkscan(int* __restrict__ chunksum, int nchunks, Ctl* ctl, int setctl) {
  __shared__ int s[1024];
  int t = threadIdx.x;
  int v = (t < nchunks) ? chunksum[t] : 0;
  s[t] = v;
  __syncthreads();
  for (int off = 1; off < 1024; off <<= 1) {
    int add = (t >= off) ? s[t - off] : 0;
    __syncthreads();
    s[t] += add;
    __syncthreads();
  }
  if (t < nchunks) chunksum[t] = s[t] - v;  // exclusive
  if (setctl && t == 1023) {
    int total = s[1023];
    ctl->begin = 0; ctl->end = total; ctl->count = total; ctl->done = 0;
  }
}

__global__ void k_desc_offsets(const int* __restrict__ vals, const int* __restrict__ chunkoff,
                               int* __restrict__ offs, int* __restrict__ cursor, int n) {
  __shared__ int s[512];
  int t = threadIdx.x;
  int i = blockIdx.x * 512 + t;
  int v = (i < n) ? vals[i] : 0;
  s[t] = v;
  __syncthreads();
  for (int off = 1; off < 512; off <<= 1) {
    int add = (t >= off) ? s[t - off] : 0;
    __syncthreads();
    s[t] += add;
    __syncthreads();
  }
  if (i < n) {
    int excl = s[t] - v + chunkoff[blockIdx.x];
    offs[i] = excl;
    cursor[i] = excl;
  }
}

__global__ void k_peak_emit(const int* __restrict__ notpeak, const int* __restrict__ chunkoff,
                            const int* __restrict__ batch, int* __restrict__ pairs_v,
                            int* __restrict__ pairs_c, int* __restrict__ visit_level,
                            int* __restrict__ cbatch, float* __restrict__ out_cb,
                            int n, int P, int cap) {
  __shared__ int s[512];
  int t = threadIdx.x;
  int i = blockIdx.x * 512 + t;
  int v = (i < n) ? (notpeak[i] == 0 ? 1 : 0) : 0;
  s[t] = v;
  __syncthreads();
  for (int off = 1; off < 512; off <<= 1) {
    int add = (t >= off) ? s[t - off] : 0;
    __syncthreads();
    s[t] += add;
    __syncthreads();
  }
  if (i < n && v) {
    int r = s[t] - 1 + chunkoff[blockIdx.x];
    if (r < cap) { pairs_v[r] = i; pairs_c[r] = r; }
    visit_level[i] = 0;
    if (r < P) {
      int bt = batch[i];
      cbatch[r] = bt;
      out_cb[r] = (float)bt;
    }
  }
}

__global__ void k_fill(const int* __restrict__ ei, const float* __restrict__ z,
                       int* __restrict__ cursor, int* __restrict__ adj, int E) {
  int i = blockIdx.x * blockDim.x + threadIdx.x;
  if (i >= E) return;
  int s = ei[i], d = ei[E + i];
  if (z[d] <= z[s]) {
    int pos = atomicAdd(&cursor[s], 1);
    adj[pos] = d;
  }
}

// one BFS level: expand frontier pairs [begin,end); accept v if not visited in an
// earlier level (atomicMin); dedup (v,c) in a global hash set; append accepted
// pairs; last finishing block advances the frontier window.
__global__ void k_bfs(const int* __restrict__ adj, const int* __restrict__ offs,
                      const int* __restrict__ cnt, int* __restrict__ visit_level,
                      unsigned long long* __restrict__ hash, unsigned hmask,
                      int* __restrict__ pairs_v, int* __restrict__ pairs_c, int cap,
                      Ctl* ctl, int level) {
  int b = ctl->begin, e = ctl->end;
  int tid = blockIdx.x * blockDim.x + threadIdx.x;
  int nth = gridDim.x * blockDim.x;
  for (int i = b + tid; i < e; i += nth) {
    int u = pairs_v[i], c = pairs_c[i];
    int o = offs[u], oc = cnt[u];
    for (int j = 0; j < oc; j++) {
      int v = adj[o + j];
      int old = atomicMin(&visit_level[v], level);
      if (old >= level) {
        unsigned long long key = ((unsigned long long)(unsigned)v << 32) | (unsigned)c;
        unsigned long long h = key * 0x9E3779B97F4A7C15ull;
        unsigned slot = (unsigned)(h >> 32) & hmask;
        bool inserted = false;
        while (true) {
          unsigned long long prev = atomicCAS(&hash[slot], 0xFFFFFFFFFFFFFFFFull, key);
          if (prev == 0xFFFFFFFFFFFFFFFFull) { inserted = true; break; }
          if (prev == key) break;
          slot = (slot + 1) & hmask;
        }
        if (inserted) {
          int idx = atomicAdd(&ctl->count, 1);
          if (idx < cap) { pairs_v[idx] = v; pairs_c[idx] = c; }
        }
      }
    }
  }
  __syncthreads();
  if (threadIdx.x == 0) {
    __threadfence();
    if (atomicAdd(&ctl->done, 1) == gridDim.x - 1) {
      int c2 = atomicAdd(&ctl->count, 0);
      if (c2 > cap) c2 = cap;
      ctl->begin = e;
      ctl->end = c2;
      ctl->done = 0;
      __threadfence();
    }
  }
}

// wave per pair: per-cluster elev max + per-feature x max (encoded-uint atomics)
__global__ void k_pairmax(const int* __restrict__ pairs_v, const int* __restrict__ pairs_c,
                          const Ctl* __restrict__ ctl, int cap,
                          const float* __restrict__ x, const float* __restrict__ elev,
                          unsigned* __restrict__ max_elev_enc,
                          unsigned* __restrict__ max_x_enc, int C) {
  int T = ctl->count;
  if (T > cap) T = cap;
  int lane = threadIdx.x & 63;
  int gw = (blockIdx.x * blockDim.x + threadIdx.x) >> 6;
  int nw = (gridDim.x * blockDim.x) >> 6;
  for (int i = gw; i < T; i += nw) {
    int v = pairs_v[i], c = pairs_c[i];
    if (lane == 0) atomicMax(&max_elev_enc[c], encf(elev[v]));
    const float* xr = x + (size_t)v * C;
    unsigned* mr = max_x_enc + (size_t)c * C;
    for (int f = lane; f < C; f += 64) atomicMax(&mr[f], encf(xr[f]));
  }
}

// single-block cluster softmax over batches
__global__ void k_cnorm(const unsigned* __restrict__ max_elev_enc, const int* __restrict__ cbatch,
                        float* __restrict__ normed, int P) {
  __shared__ unsigned cm[1024];
  __shared__ float cs[1024];
  int t = threadIdx.x;
  for (int i = t; i < 1024; i += blockDim.x) { cm[i] = 0u; cs[i] = 0.f; }
  __syncthreads();
  for (int i = t; i < P; i += blockDim.x) atomicMax(&cm[cbatch[i] & 1023], max_elev_enc[i]);
  __syncthreads();
  for (int i = t; i < P; i += blockDim.x) {
    int bt = cbatch[i] & 1023;
    atomicAdd(&cs[bt], expf(decf(max_elev_enc[i]) - decf(cm[bt])));
  }
  __syncthreads();
  for (int i = t; i < P; i += blockDim.x) {
    int bt = cbatch[i] & 1023;
    normed[i] = expf(decf(max_elev_enc[i]) - decf(cm[bt])) / cs[bt];
  }
}

__global__ void k_out(const unsigned* __restrict__ max_x_enc, const float* __restrict__ normed,
                      float* __restrict__ out, int n, int C) {
  int i = blockIdx.x * blockDim.x + threadIdx.x;
  if (i < n) out[i] = decf(max_x_enc[i]) * normed[i / C];
}

extern "C" void kernel_launch(void* const* d_in, const int* in_sizes, int n_in,
                              void* d_out, int out_size, void* d_ws, size_t ws_size,
                              hipStream_t stream) {
  const float* x = (const float*)d_in[0];
  const int* ei = (const int*)d_in[1];
  const int* batch = (const int*)d_in[2];
  const float* W = (const float*)d_in[3];
  const float* b = (const float*)d_in[4];

  const int N = in_sizes[2];
  const int C = in_sizes[0] / N;
  const int E = in_sizes[1] / 2;
  const int P = (out_size - N) / (C + 1);

  float* out = (float*)d_out;
  float* out_pooled = out;                    // P*C
  float* out_cb = out + (size_t)P * C;        // P
  float* out_elev = out_cb + P;               // N

  // ---- workspace carve-up ----
  char* w = (char*)d_ws;
  size_t off = 0;
  auto alloc = [&](size_t bytes) -> void* {
    off = (off + 255) & ~(size_t)255;
    void* p = (void*)(w + off);
    off += bytes;
    return p;
  };
  float* z          = (float*)alloc((size_t)N * 4);
  float* e          = (float*)alloc((size_t)N * 4);
  int* notpeak      = (int*)alloc((size_t)N * 4);
  int* desc_cnt     = (int*)alloc((size_t)N * 4);
  int* desc_off     = (int*)alloc((size_t)N * 4);
  int* cursor       = (int*)alloc((size_t)N * 4);
  int* visit        = (int*)alloc((size_t)N * 4);
  const int nchunks = (N + 511) / 512;
  int* chunksum     = (int*)alloc((size_t)nchunks * 4);
  int* cbatch       = (int*)alloc((size_t)P * 4);
  unsigned* bmax    = (unsigned*)alloc(1024 * 4);
  float* bsum       = (float*)alloc(1024 * 4);
  float* normed     = (float*)alloc((size_t)P * 4);
  unsigned* melev   = (unsigned*)alloc((size_t)P * 4);
  unsigned* mx      = (unsigned*)alloc((size_t)P * C * 4);
  Ctl* ctl          = (Ctl*)alloc(sizeof(Ctl));
  int* adj          = (int*)alloc((size_t)E * 4);

  size_t remain = (ws_size > off + 1024) ? (ws_size - off - 1024) : 0;
  size_t H = 65536;  // hash entries (pow2); pairs cap = H/2; bytes = 12*H
  while ((H << 1) * 12 <= remain && (H << 1) <= (size_t)(1u << 22)) H <<= 1;
  unsigned long long* hash = (unsigned long long*)alloc(H * 8);
  int cap = (int)(H >> 1);
  int* pairs_v = (int*)alloc((size_t)cap * 4);
  int* pairs_c = (int*)alloc((size_t)cap * 4);
  const unsigned hmask = (unsigned)(H - 1);

  // ---- per-call inits (ws is re-poisoned 0xAA before every launch) ----
  hipMemsetAsync(notpeak, 0, (size_t)N * 4, stream);
  hipMemsetAsync(desc_cnt, 0, (size_t)N * 4, stream);
  hipMemsetAsync(visit, 0x7F, (size_t)N * 4, stream);   // 0x7f7f7f7f = "inf"
  hipMemsetAsync(bmax, 0, 1024 * 4, stream);            // enc 0 = -inf
  hipMemsetAsync(bsum, 0, 1024 * 4, stream);
  hipMemsetAsync(melev, 0, (size_t)P * 4, stream);
  hipMemsetAsync(mx, 0, (size_t)P * C * 4, stream);
  hipMemsetAsync(hash, 0xFF, H * 8, stream);
  hipMemsetAsync(ctl, 0, sizeof(Ctl), stream);

  // ---- z + batch max ----
  k_z<<<512, 256, 0, stream>>>(x, W, b, batch, z, bmax, N, C);
  // ---- exp + batch sum ----
  int nblkN = (N + 255) / 256;
  k_e<<<nblkN, 256, 0, stream>>>(z, batch, bmax, e, bsum, N);
  // ---- elev -> d_out ----
  k_elev<<<nblkN, 256, 0, stream>>>(e, batch, bsum, out_elev, N);
  // ---- peaks + descending degree ----
  int nblkE = (E + 255) / 256;
  k_edges<<<nblkE, 256, 0, stream>>>(ei, z, notpeak, desc_cnt, E);
  // ---- CSR offsets for descending adjacency ----
  k_chunksum<<<nchunks, 512, 0, stream>>>(desc_cnt, 0, N, chunksum);
  k_chunkscan<<<1, 1024, 0, stream>>>(chunksum, nchunks, nullptr, 0);
  k_desc_offsets<<<nchunks, 512, 0, stream>>>(desc_cnt, chunksum, desc_off, cursor, N);
  k_fill<<<nblkE, 256, 0, stream>>>(ei, z, cursor, adj, E);
  // ---- peak ranks -> initial frontier pairs + cb output ----
  k_chunksum<<<nchunks, 512, 0, stream>>>(notpeak, 1, N, chunksum);
  k_chunkscan<<<1, 1024, 0, stream>>>(chunksum, nchunks, ctl, 1);
  k_peak_emit<<<nchunks, 512, 0, stream>>>(notpeak, chunksum, batch, pairs_v, pairs_c,
                                           visit, cbatch, out_cb, N, P, cap);
  // ---- level-synchronous watershed BFS ----
  const int MAX_LEVELS = 48;
  for (int lvl = 1; lvl <= MAX_LEVELS; ++lvl) {
    k_bfs<<<128, 256, 0, stream>>>(adj, desc_off, desc_cnt, visit, hash, hmask,
                                   pairs_v, pairs_c, cap, ctl, lvl);
  }
  // ---- per-cluster maxima over all (member, cluster) pairs ----
  k_pairmax<<<512, 256, 0, stream>>>(pairs_v, pairs_c, ctl, cap, x, out_elev, melev, mx, C);
  // ---- cluster softmax ----
  k_cnorm<<<1, 1024, 0, stream>>>(melev, cbatch, normed, P);
  // ---- pooled output ----
  int nPC = P * C;
  k_out<<<(nPC + 255) / 256, 256, 0, stream>>>(mx, normed, out_pooled, nPC, C);
}

// Round 2
// 1089.571 us; speedup vs baseline: 1.4690x; 1.4690x over previous
//
#include <hip/hip_runtime.h>
#include <hip/hip_bf16.h>
#include <stdint.h>

// ---------------------------------------------------------------------------
// TopoPool: z = x@W.T + b ; seg-softmax elev ; peaks (no higher in-neighbor) ;
// persistent level-synchronous watershed BFS along descending edges (ties ->
// both) ; CSR-grouped per-cluster per-feature max ; cluster softmax ;
// pooled = max_x * normed.  Comparisons use z (monotone to elev per batch).
// ---------------------------------------------------------------------------

struct Ctl { int begin; int end; int count; int done; };

__device__ __forceinline__ unsigned encf(float f) {
  unsigned u = __float_as_uint(f);
  return (u & 0x80000000u) ? ~u : (u | 0x80000000u);
}
__device__ __forceinline__ float decf(unsigned u) {
  unsigned v = (u & 0x80000000u) ? (u & 0x7fffffffu) : ~u;
  return __uint_as_float(v);
}
__device__ __forceinline__ int aload(const int* p) {
  return __hip_atomic_load(p, __ATOMIC_RELAXED, __HIP_MEMORY_SCOPE_AGENT);
}
__device__ __forceinline__ void astore(int* p, int v) {
  __hip_atomic_store(p, v, __ATOMIC_RELAXED, __HIP_MEMORY_SCOPE_AGENT);
}

// wave-per-node dot(x[v], W) + b; per-block LDS batch max -> global encoded max
__global__ void k_z(const float* __restrict__ x, const float* __restrict__ W,
                    const float* __restrict__ b, const int* __restrict__ batch,
                    float* __restrict__ z, unsigned* __restrict__ bmax_enc,
                    int N, int C) {
  __shared__ unsigned smax[1024];
  for (int i = threadIdx.x; i < 1024; i += blockDim.x) smax[i] = 0u;
  __syncthreads();
  int lane = threadIdx.x & 63;
  int wid = threadIdx.x >> 6;
  int wavesPerBlock = blockDim.x >> 6;
  int gw = blockIdx.x * wavesPerBlock + wid;
  int nw = gridDim.x * wavesPerBlock;
  float b0 = b[0];
  for (int v = gw; v < N; v += nw) {
    const float* xr = x + (size_t)v * C;
    float acc = 0.f;
    for (int f = lane * 4; f < C; f += 256) {
      float4 xv = *(const float4*)(xr + f);
      float4 wv = *(const float4*)(W + f);
      acc += xv.x * wv.x + xv.y * wv.y + xv.z * wv.z + xv.w * wv.w;
    }
    for (int off = 32; off > 0; off >>= 1) acc += __shfl_xor(acc, off, 64);
    if (lane == 0) {
      float zv = acc + b0;
      z[v] = zv;
      atomicMax(&smax[batch[v] & 1023], encf(zv));
    }
  }
  __syncthreads();
  for (int i = threadIdx.x; i < 1024; i += blockDim.x)
    if (smax[i]) atomicMax(&bmax_enc[i], smax[i]);
}

__global__ void k_e(const float* __restrict__ z, const int* __restrict__ batch,
                    const unsigned* __restrict__ bmax_enc, float* __restrict__ e,
                    float* __restrict__ bsum, int N) {
  __shared__ float ssum[1024];
  for (int i = threadIdx.x; i < 1024; i += blockDim.x) ssum[i] = 0.f;
  __syncthreads();
  int i = blockIdx.x * blockDim.x + threadIdx.x;
  if (i < N) {
    int bt = batch[i] & 1023;
    float ev = expf(z[i] - decf(bmax_enc[bt]));
    e[i] = ev;
    atomicAdd(&ssum[bt], ev);
  }
  __syncthreads();
  for (int t = threadIdx.x; t < 1024; t += blockDim.x)
    if (ssum[t] != 0.f) atomicAdd(&bsum[t], ssum[t]);
}

__global__ void k_elev(const float* __restrict__ e, const int* __restrict__ batch,
                       const float* __restrict__ bsum, float* __restrict__ elev_out, int N) {
  int i = blockIdx.x * blockDim.x + threadIdx.x;
  if (i < N) elev_out[i] = e[i] / bsum[batch[i] & 1023];
}

// per directed edge: notpeak[dst] if z[dst] < z[src]; count descending out-edges of src
__global__ void k_edges(const int* __restrict__ ei, const float* __restrict__ z,
                        int* __restrict__ notpeak, int* __restrict__ desc_cnt, int E) {
  int i = blockIdx.x * blockDim.x + threadIdx.x;
  if (i >= E) return;
  int s = ei[i], d = ei[E + i];
  float zs = z[s], zd = z[d];
  if (zd < zs) notpeak[d] = 1;
  if (zd <= zs) atomicAdd(&desc_cnt[s], 1);
}

// ---- generic chunked exclusive scan (chunk = 512, nchunks <= 1024) ----
__global__ void k_chunksum(const int* __restrict__ vals, int mode, int n,
                           int* __restrict__ chunksum) {
  __shared__ int s[512];
  int t = threadIdx.x;
  int i = blockIdx.x * 512 + t;
  int v = 0;
  if (i < n) { int a = vals[i]; v = mode ? (a == 0 ? 1 : 0) : a; }
  s[t] = v;
  __syncthreads();
  for (int off = 256; off > 0; off >>= 1) {
    if (t < off) s[t] += s[t + off];
    __syncthreads();
  }
  if (t == 0) chunksum[blockIdx.x] = s[0];
}

__global__ void k_chunkscan(int* __restrict__ chunksum, int nchunks, Ctl* ctl, int setctl) {
  __shared__ int s[1024];
  int t = threadIdx.x;
  int v = (t < nchunks) ? chunksum[t] : 0;
  s[t] = v;
  __syncthreads();
  for (int off = 1; off < 1024; off <<= 1) {
    int add = (t >= off) ? s[t - off] : 0;
    __syncthreads();
    s[t] += add;
    __syncthreads();
  }
  if (t < nchunks) chunksum[t] = s[t] - v;  // exclusive
  if (setctl && t == 1023) {
    int total = s[1023];
    ctl->begin = 0; ctl->end = total; ctl->count = total; ctl->done = 0;
  }
}

__global__ void k_offsets(const int* __restrict__ vals, const int* __restrict__ chunkoff,
                          int* __restrict__ offs, int* __restrict__ cursor, int n) {
  __shared__ int s[512];
  int t = threadIdx.x;
  int i = blockIdx.x * 512 + t;
  int v = (i < n) ? vals[i] : 0;
  s[t] = v;
  __syncthreads();
  for (int off = 1; off < 512; off <<= 1) {
    int add = (t >= off) ? s[t - off] : 0;
    __syncthreads();
    s[t] += add;
    __syncthreads();
  }
  if (i < n) {
    int excl = s[t] - v + chunkoff[blockIdx.x];
    offs[i] = excl;
    cursor[i] = excl;
  }
}

__global__ void k_peak_emit(const int* __restrict__ notpeak, const int* __restrict__ chunkoff,
                            const int* __restrict__ batch, int* __restrict__ pairs_v,
                            int* __restrict__ pairs_c, int* __restrict__ visit_level,
                            int* __restrict__ cbatch, float* __restrict__ out_cb,
                            int n, int P, int cap) {
  __shared__ int s[512];
  int t = threadIdx.x;
  int i = blockIdx.x * 512 + t;
  int v = (i < n) ? (notpeak[i] == 0 ? 1 : 0) : 0;
  s[t] = v;
  __syncthreads();
  for (int off = 1; off < 512; off <<= 1) {
    int add = (t >= off) ? s[t - off] : 0;
    __syncthreads();
    s[t] += add;
    __syncthreads();
  }
  if (i < n && v) {
    int r = s[t] - 1 + chunkoff[blockIdx.x];
    if (r < cap) { pairs_v[r] = i; pairs_c[r] = r; }
    visit_level[i] = 0;
    if (r < P) {
      int bt = batch[i];
      cbatch[r] = bt;
      out_cb[r] = (float)bt;
    }
  }
}

__global__ void k_fill(const int* __restrict__ ei, const float* __restrict__ z,
                       int* __restrict__ cursor, int* __restrict__ adj, int E) {
  int i = blockIdx.x * blockDim.x + threadIdx.x;
  if (i >= E) return;
  int s = ei[i], d = ei[E + i];
  if (z[d] <= z[s]) {
    int pos = atomicAdd(&cursor[s], 1);
    adj[pos] = d;
  }
}

// persistent BFS: all levels in one kernel, grid barrier via device atomics.
// 128 blocks x 256 threads on 256 CUs -> co-resident by construction.
__global__ void __launch_bounds__(256, 1)
k_bfs_persist(const int* __restrict__ adj, const int* __restrict__ offs,
              const int* __restrict__ cnt, int* __restrict__ visit_level,
              unsigned long long* __restrict__ hash, unsigned hmask,
              int* __restrict__ pairs_v, int* __restrict__ pairs_c, int cap,
              Ctl* ctl, int* bar) {
  __shared__ int s_b, s_e;
  const int nb = gridDim.x;
  int gen = 0;
  for (int level = 1; level <= 64; ++level) {
    if (threadIdx.x == 0) { s_b = aload(&ctl->begin); s_e = aload(&ctl->end); }
    __syncthreads();
    int b = s_b, e = s_e;
    if (b >= e) break;  // uniform across blocks
    int tid = blockIdx.x * blockDim.x + threadIdx.x;
    int nth = nb * blockDim.x;
    for (int i = b + tid; i < e; i += nth) {
      int u = aload(&pairs_v[i]), c = aload(&pairs_c[i]);
      int o = offs[u], oc = cnt[u];
      for (int j = 0; j < oc; j++) {
        int v = adj[o + j];
        int old = atomicMin(&visit_level[v], level);
        if (old >= level) {
          unsigned long long key = ((unsigned long long)(unsigned)v << 32) | (unsigned)c;
          unsigned long long h = key * 0x9E3779B97F4A7C15ull;
          unsigned slot = (unsigned)(h >> 32) & hmask;
          bool inserted = false;
          while (true) {
            unsigned long long prev = atomicCAS(&hash[slot], 0xFFFFFFFFFFFFFFFFull, key);
            if (prev == 0xFFFFFFFFFFFFFFFFull) { inserted = true; break; }
            if (prev == key) break;
            slot = (slot + 1) & hmask;
          }
          if (inserted) {
            int idx = atomicAdd(&ctl->count, 1);
            if (idx < cap) { astore(&pairs_v[idx], v); astore(&pairs_c[idx], c); }
          }
        }
      }
    }
    // ---- grid barrier; last block advances the frontier window ----
    __threadfence();
    __syncthreads();
    if (threadIdx.x == 0) {
      if (atomicAdd(&bar[0], 1) == nb - 1) {
        atomicExch(&bar[0], 0);
        int c2 = atomicAdd(&ctl->count, 0);
        if (c2 > cap) c2 = cap;
        astore(&ctl->begin, e);
        astore(&ctl->end, c2);
        __threadfence();
        atomicAdd(&bar[1], 1);
      } else {
        while (atomicAdd(&bar[1], 0) <= gen) { __builtin_amdgcn_s_sleep(8); }
      }
    }
    gen++;
    __syncthreads();
  }
}

// ---- CSR grouping of (member, cluster) pairs by cluster ----
__global__ void k_ccount(const int* __restrict__ pairs_c, const Ctl* __restrict__ ctl,
                         int cap, int* __restrict__ ccount) {
  int T = ctl->count; if (T > cap) T = cap;
  int tid = blockIdx.x * blockDim.x + threadIdx.x;
  int nth = gridDim.x * blockDim.x;
  for (int i = tid; i < T; i += nth) atomicAdd(&ccount[pairs_c[i]], 1);
}

__global__ void k_scatter(const int* __restrict__ pairs_v, const int* __restrict__ pairs_c,
                          const Ctl* __restrict__ ctl, int cap,
                          int* __restrict__ ccur, int* __restrict__ plist) {
  int T = ctl->count; if (T > cap) T = cap;
  int tid = blockIdx.x * blockDim.x + threadIdx.x;
  int nth = gridDim.x * blockDim.x;
  for (int i = tid; i < T; i += nth) {
    int pos = atomicAdd(&ccur[pairs_c[i]], 1);
    plist[pos] = pairs_v[i];
  }
}

// block (4 waves) per cluster: stream member rows coalesced, max in registers,
// LDS-combine waves, write each output row exactly once.
__global__ void k_creduce(const int* __restrict__ plist, const int* __restrict__ coff,
                          const int* __restrict__ ccnt, const float* __restrict__ x,
                          const float* __restrict__ elev, float* __restrict__ melev,
                          float* __restrict__ mx, int C, int P) {
  __shared__ float red[1024];
  __shared__ float rede[4];
  int c = blockIdx.x;
  if (c >= P) return;
  int lane = threadIdx.x & 63, wid = threadIdx.x >> 6;
  int o = coff[c], n = ccnt[c];
  float4 m4 = make_float4(-INFINITY, -INFINITY, -INFINITY, -INFINITY);
  float me = -INFINITY;
  for (int j = wid; j < n; j += 4) {
    int v = plist[o + j];
    float4 xv = ((const float4*)(x + (size_t)v * C))[lane];
    m4.x = fmaxf(m4.x, xv.x); m4.y = fmaxf(m4.y, xv.y);
    m4.z = fmaxf(m4.z, xv.z); m4.w = fmaxf(m4.w, xv.w);
    if (lane == 0) me = fmaxf(me, elev[v]);
  }
  ((float4*)red)[wid * 64 + lane] = m4;
  if (lane == 0) rede[wid] = me;
  __syncthreads();
  if (wid == 0) {
    float4 a = ((float4*)red)[lane];
    for (int w = 1; w < 4; w++) {
      float4 bb = ((float4*)red)[w * 64 + lane];
      a.x = fmaxf(a.x, bb.x); a.y = fmaxf(a.y, bb.y);
      a.z = fmaxf(a.z, bb.z); a.w = fmaxf(a.w, bb.w);
    }
    ((float4*)(mx + (size_t)c * C))[lane] = a;
    if (lane == 0)
      melev[c] = fmaxf(fmaxf(rede[0], rede[1]), fmaxf(rede[2], rede[3]));
  }
}

// single-block cluster softmax over batches
__global__ void k_cnorm(const float* __restrict__ melev, const int* __restrict__ cbatch,
                        float* __restrict__ normed, int P) {
  __shared__ unsigned cm[1024];
  __shared__ float cs[1024];
  int t = threadIdx.x;
  for (int i = t; i < 1024; i += blockDim.x) { cm[i] = 0u; cs[i] = 0.f; }
  __syncthreads();
  for (int i = t; i < P; i += blockDim.x) atomicMax(&cm[cbatch[i] & 1023], encf(melev[i]));
  __syncthreads();
  for (int i = t; i < P; i += blockDim.x) {
    int bt = cbatch[i] & 1023;
    atomicAdd(&cs[bt], expf(melev[i] - decf(cm[bt])));
  }
  __syncthreads();
  for (int i = t; i < P; i += blockDim.x) {
    int bt = cbatch[i] & 1023;
    normed[i] = expf(melev[i] - decf(cm[bt])) / cs[bt];
  }
}

__global__ void k_out(const float* __restrict__ mx, const float* __restrict__ normed,
                      float* __restrict__ out, int n, int C) {
  int i = blockIdx.x * blockDim.x + threadIdx.x;
  if (i < n) out[i] = mx[i] * normed[i / C];
}

extern "C" void kernel_launch(void* const* d_in, const int* in_sizes, int n_in,
                              void* d_out, int out_size, void* d_ws, size_t ws_size,
                              hipStream_t stream) {
  const float* x = (const float*)d_in[0];
  const int* ei = (const int*)d_in[1];
  const int* batch = (const int*)d_in[2];
  const float* W = (const float*)d_in[3];
  const float* b = (const float*)d_in[4];

  const int N = in_sizes[2];
  const int C = in_sizes[0] / N;
  const int E = in_sizes[1] / 2;
  const int P = (out_size - N) / (C + 1);

  float* out = (float*)d_out;
  float* out_pooled = out;                    // P*C
  float* out_cb = out + (size_t)P * C;        // P
  float* out_elev = out_cb + P;               // N

  // ---- workspace carve-up ----
  char* w = (char*)d_ws;
  size_t off = 0;
  auto alloc = [&](size_t bytes) -> void* {
    off = (off + 255) & ~(size_t)255;
    void* p = (void*)(w + off);
    off += bytes;
    return p;
  };
  float* z          = (float*)alloc((size_t)N * 4);
  float* e          = (float*)alloc((size_t)N * 4);
  int* notpeak      = (int*)alloc((size_t)N * 4);
  int* desc_cnt     = (int*)alloc((size_t)N * 4);
  int* desc_off     = (int*)alloc((size_t)N * 4);
  int* cursor       = (int*)alloc((size_t)N * 4);
  int* visit        = (int*)alloc((size_t)N * 4);
  const int nchunks = (N + 511) / 512;
  int* chunksum     = (int*)alloc((size_t)nchunks * 4);
  int* cbatch       = (int*)alloc((size_t)P * 4);
  unsigned* bmax    = (unsigned*)alloc(1024 * 4);
  float* bsum       = (float*)alloc(1024 * 4);
  float* normed     = (float*)alloc((size_t)P * 4);
  float* melev      = (float*)alloc((size_t)P * 4);
  float* mx         = (float*)alloc((size_t)P * C * 4);
  int* ccount       = (int*)alloc((size_t)P * 4);
  int* coff         = (int*)alloc((size_t)P * 4);
  int* ccur         = (int*)alloc((size_t)P * 4);
  Ctl* ctl          = (Ctl*)alloc(sizeof(Ctl));
  int* bar          = (int*)alloc(2 * 4);
  int* adj          = (int*)alloc((size_t)E * 4);

  size_t remain = (ws_size > off + 1024) ? (ws_size - off - 1024) : 0;
  size_t H = 65536;  // hash entries (pow2); pairs cap = H/2; bytes ~ 18*H
  while ((H << 1) * 18 <= remain && (H << 1) <= (size_t)(1u << 22)) H <<= 1;
  unsigned long long* hash = (unsigned long long*)alloc(H * 8);
  int cap = (int)(H >> 1);
  int* pairs_v = (int*)alloc((size_t)cap * 4);
  int* pairs_c = (int*)alloc((size_t)cap * 4);
  int* plist   = (int*)alloc((size_t)cap * 4);
  const unsigned hmask = (unsigned)(H - 1);

  // ---- per-call inits (ws is re-poisoned 0xAA before every launch) ----
  hipMemsetAsync(notpeak, 0, (size_t)N * 4, stream);
  hipMemsetAsync(desc_cnt, 0, (size_t)N * 4, stream);
  hipMemsetAsync(visit, 0x7F, (size_t)N * 4, stream);   // 0x7f7f7f7f = "inf"
  hipMemsetAsync(bmax, 0, 1024 * 4, stream);            // enc 0 = -inf
  hipMemsetAsync(bsum, 0, 1024 * 4, stream);
  hipMemsetAsync(ccount, 0, (size_t)P * 4, stream);
  hipMemsetAsync(hash, 0xFF, H * 8, stream);
  hipMemsetAsync(ctl, 0, sizeof(Ctl), stream);
  hipMemsetAsync(bar, 0, 2 * 4, stream);

  // ---- z + batch max ----
  k_z<<<512, 256, 0, stream>>>(x, W, b, batch, z, bmax, N, C);
  // ---- exp + batch sum ----
  int nblkN = (N + 255) / 256;
  k_e<<<nblkN, 256, 0, stream>>>(z, batch, bmax, e, bsum, N);
  // ---- elev -> d_out ----
  k_elev<<<nblkN, 256, 0, stream>>>(e, batch, bsum, out_elev, N);
  // ---- peaks + descending degree ----
  int nblkE = (E + 255) / 256;
  k_edges<<<nblkE, 256, 0, stream>>>(ei, z, notpeak, desc_cnt, E);
  // ---- CSR offsets for descending adjacency ----
  k_chunksum<<<nchunks, 512, 0, stream>>>(desc_cnt, 0, N, chunksum);
  k_chunkscan<<<1, 1024, 0, stream>>>(chunksum, nchunks, nullptr, 0);
  k_offsets<<<nchunks, 512, 0, stream>>>(desc_cnt, chunksum, desc_off, cursor, N);
  k_fill<<<nblkE, 256, 0, stream>>>(ei, z, cursor, adj, E);
  // ---- peak ranks -> initial frontier pairs + cb output ----
  k_chunksum<<<nchunks, 512, 0, stream>>>(notpeak, 1, N, chunksum);
  k_chunkscan<<<1, 1024, 0, stream>>>(chunksum, nchunks, ctl, 1);
  k_peak_emit<<<nchunks, 512, 0, stream>>>(notpeak, chunksum, batch, pairs_v, pairs_c,
                                           visit, cbatch, out_cb, N, P, cap);
  // ---- watershed BFS: all levels in one persistent kernel ----
  k_bfs_persist<<<128, 256, 0, stream>>>(adj, desc_off, desc_cnt, visit, hash, hmask,
                                         pairs_v, pairs_c, cap, ctl, bar);
  // ---- CSR-group pairs by cluster ----
  k_ccount<<<1024, 256, 0, stream>>>(pairs_c, ctl, cap, ccount);
  const int nchunksP = (P + 511) / 512;
  k_chunksum<<<nchunksP, 512, 0, stream>>>(ccount, 0, P, chunksum);
  k_chunkscan<<<1, 1024, 0, stream>>>(chunksum, nchunksP, nullptr, 0);
  k_offsets<<<nchunksP, 512, 0, stream>>>(ccount, chunksum, coff, ccur, P);
  k_scatter<<<1024, 256, 0, stream>>>(pairs_v, pairs_c, ctl, cap, ccur, plist);
  // ---- per-cluster maxima: block per cluster, single write ----
  k_creduce<<<P, 256, 0, stream>>>(plist, coff, ccount, x, out_elev, melev, mx, C, P);
  // ---- cluster softmax ----
  k_cnorm<<<1, 1024, 0, stream>>>(melev, cbatch, normed, P);
  // ---- pooled output ----
  int nPC = P * C;
  k_out<<<(nPC + 255) / 256, 256, 0, stream>>>(mx, normed, out_pooled, nPC, C);
}